// Round 5
// baseline (471.666 us; speedup 1.0000x reference)
//
#include <hip/hip_runtime.h>

// Morphological dilation (max-plus 3x3 conv), zero-padded.
// x: (B=4, C=64, H=512, W=512) fp32, weights: (C=64, 3, 3) fp32.
// out[b,c,h,w] = max_{i,j in 0..2} ( xp[b,c,h-1+i,w-1+j] + wt[c,i,j] ),
// zero-padded (nn.Unfold semantics) — padded zeros DO participate.
//
// R5: 4(rows)x8(cols) tile per thread. One wave (64 lanes x 8 cols)
// covers a full 512-wide row => perfectly contiguous 2KB wave loads.
// 24 loads + 8 NT stores per 512B of output (R3 was 22 VMEM / 256B).
// NT stores keep the write-only output from evicting input halos in L2.

#define BB 4
#define CC 64
#define HH 512
#define WW 512
#define W8 (WW / 8)   // 64 col-groups = exactly one wave per row-strip
#define RB 4          // output rows per thread
#define HB (HH / RB)  // 128 row-blocks

typedef float vfloat4 __attribute__((ext_vector_type(4)));

__global__ __launch_bounds__(256) void morph_dilate_kernel(
    const float* __restrict__ x,
    const float* __restrict__ wts,
    float* __restrict__ out) {
    int tid = blockIdx.x * blockDim.x + threadIdx.x;
    // total threads = B*C * HB * W8 = 256*128*64 = 2,097,152
    int wi    = tid & (W8 - 1);          // col-group 0..63 (== lane)
    int w8    = wi * 8;
    int hb    = (tid >> 6) & (HB - 1);   // row-block 0..127
    int h0    = hb * RB;
    int plane = tid >> 13;               // b*C + c, 0..255
    int c     = plane & (CC - 1);

    const float* xplane = x + (size_t)plane * (HH * WW);
    const float* wt = wts + c * 9;

    float w00 = wt[0], w01 = wt[1], w02 = wt[2];
    float w10 = wt[3], w11 = wt[4], w12 = wt[5];
    float w20 = wt[6], w21 = wt[7], w22 = wt[8];

    // load 6 input rows (h0-1 .. h0+4): cols w8-1 .. w8+8 (10 floats)
    float v[6][10];
#pragma unroll
    for (int i = 0; i < 6; ++i) {
        int r = h0 - 1 + i;
        if (r >= 0 && r < HH) {
            const float* xrow = xplane + r * WW;
            v[i][0] = (w8 > 0) ? xrow[w8 - 1] : 0.0f;
            vfloat4 m0 = *reinterpret_cast<const vfloat4*>(xrow + w8);
            vfloat4 m1 = *reinterpret_cast<const vfloat4*>(xrow + w8 + 4);
            v[i][1] = m0.x; v[i][2] = m0.y; v[i][3] = m0.z; v[i][4] = m0.w;
            v[i][5] = m1.x; v[i][6] = m1.y; v[i][7] = m1.z; v[i][8] = m1.w;
            v[i][9] = (w8 + 8 < WW) ? xrow[w8 + 8] : 0.0f;
        } else {
#pragma unroll
            for (int j = 0; j < 10; ++j) v[i][j] = 0.0f;
        }
    }

    float* oplane = out + (size_t)plane * (HH * WW);
#pragma unroll
    for (int rt = 0; rt < RB; ++rt) {
        vfloat4 o0, o1;
#pragma unroll
        for (int t = 0; t < 4; ++t) {
            float m;
            m =          v[rt + 0][t + 0] + w00;
            m = fmaxf(m, v[rt + 0][t + 1] + w01);
            m = fmaxf(m, v[rt + 0][t + 2] + w02);
            m = fmaxf(m, v[rt + 1][t + 0] + w10);
            m = fmaxf(m, v[rt + 1][t + 1] + w11);
            m = fmaxf(m, v[rt + 1][t + 2] + w12);
            m = fmaxf(m, v[rt + 2][t + 0] + w20);
            m = fmaxf(m, v[rt + 2][t + 1] + w21);
            m = fmaxf(m, v[rt + 2][t + 2] + w22);
            o0[t] = m;
        }
#pragma unroll
        for (int t = 4; t < 8; ++t) {
            float m;
            m =          v[rt + 0][t + 0] + w00;
            m = fmaxf(m, v[rt + 0][t + 1] + w01);
            m = fmaxf(m, v[rt + 0][t + 2] + w02);
            m = fmaxf(m, v[rt + 1][t + 0] + w10);
            m = fmaxf(m, v[rt + 1][t + 1] + w11);
            m = fmaxf(m, v[rt + 1][t + 2] + w12);
            m = fmaxf(m, v[rt + 2][t + 0] + w20);
            m = fmaxf(m, v[rt + 2][t + 1] + w21);
            m = fmaxf(m, v[rt + 2][t + 2] + w22);
            o1[t - 4] = m;
        }
        float* orow = oplane + (size_t)(h0 + rt) * WW + w8;
        __builtin_nontemporal_store(o0, reinterpret_cast<vfloat4*>(orow));
        __builtin_nontemporal_store(o1, reinterpret_cast<vfloat4*>(orow + 4));
    }
}

extern "C" void kernel_launch(void* const* d_in, const int* in_sizes, int n_in,
                              void* d_out, int out_size, void* d_ws, size_t ws_size,
                              hipStream_t stream) {
    const float* x   = (const float*)d_in[0];
    const float* wts = (const float*)d_in[1];
    float* out = (float*)d_out;

    int total_threads = BB * CC * HB * W8;   // 2,097,152
    int block = 256;
    int grid = total_threads / block;        // 8,192
    morph_dilate_kernel<<<grid, block, 0, stream>>>(x, wts, out);
}

// Round 6
// 436.004 us; speedup vs baseline: 1.0818x; 1.0818x over previous
//
#include <hip/hip_runtime.h>

// Morphological dilation (max-plus 3x3 conv), zero-padded.
// x: (B=4, C=64, H=512, W=512) fp32, weights: (C=64, 3, 3) fp32.
// out[b,c,h,w] = max_{i,j in 0..2} ( xp[b,c,h-1+i,w-1+j] + wt[c,i,j] ),
// zero-padded (nn.Unfold semantics) — padded zeros DO participate.
//
// R6: 8(rows)x4(cols) tile per thread. Each thread loads ONE aligned
// float4 per input row (10 rows). Left/right halo columns come from
// wave shuffles of neighbor lanes' registers; only lanes 0/63 issue a
// single predicated scalar load per row. Plain cached stores (NT store
// caused write amplification + low write BW in R3/R5).

#define BB 4
#define CC 64
#define HH 512
#define WW 512
#define W4 (WW / 4)   // 128 col-groups
#define RB 8          // output rows per thread
#define HB (HH / RB)  // 64 row-blocks

typedef float vfloat4 __attribute__((ext_vector_type(4)));

__global__ __launch_bounds__(256) void morph_dilate_kernel(
    const float* __restrict__ x,
    const float* __restrict__ wts,
    float* __restrict__ out) {
    int tid = blockIdx.x * blockDim.x + threadIdx.x;
    // total threads = 256 planes * 64 hb * 128 wi = 2,097,152
    int wi    = tid & (W4 - 1);          // col-group 0..127 (bit6 = wave half)
    int w4    = wi * 4;
    int hb    = (tid >> 7) & (HB - 1);   // row-block 0..63 (wave-uniform)
    int h0    = hb * RB;
    int plane = tid >> 13;               // b*C + c (wave-uniform)
    int c     = plane & (CC - 1);
    int lane  = threadIdx.x & 63;

    const float* xplane = x + (size_t)plane * (HH * WW);
    const float* wt = wts + c * 9;

    float w00 = wt[0], w01 = wt[1], w02 = wt[2];
    float w10 = wt[3], w11 = wt[4], w12 = wt[5];
    float w20 = wt[6], w21 = wt[7], w22 = wt[8];

    bool isl = (lane == 0);
    bool isr = (lane == 63);
    // edge column this lane would need to fetch (lane0: left, lane63: right)
    int ecol = isl ? (w4 - 1) : (w4 + 4);
    bool eneed = (isl && w4 > 0) || (isr && w4 + 4 < WW);

    // 10 input rows (h0-1 .. h0+8): mid 4 floats + left/right halo cols
    float vm[10][4];
    float vl[10], vr[10];
#pragma unroll
    for (int i = 0; i < 10; ++i) {
        int r = h0 - 1 + i;               // wave-uniform condition
        if (r >= 0 && r < HH) {
            const float* xrow = xplane + r * WW;
            vfloat4 mid = *reinterpret_cast<const vfloat4*>(xrow + w4);
            float edge = 0.0f;
            if (eneed) edge = xrow[ecol];  // masked: lanes 0 & 63 only
            float l = __shfl_up(mid.w, 1);   // lane L <- lane L-1's col w4-1
            float rgt = __shfl_down(mid.x, 1); // lane L <- lane L+1's col w4+4
            if (isl) l = edge;               // 0 when w4==0 (zero pad)
            if (isr) rgt = edge;             // 0 when w4+4==WW
            vm[i][0] = mid.x; vm[i][1] = mid.y; vm[i][2] = mid.z; vm[i][3] = mid.w;
            vl[i] = l; vr[i] = rgt;
        } else {
            vm[i][0] = vm[i][1] = vm[i][2] = vm[i][3] = 0.0f;
            vl[i] = vr[i] = 0.0f;
        }
    }

    float* oplane = out + (size_t)plane * (HH * WW);
#pragma unroll
    for (int rt = 0; rt < RB; ++rt) {
        // window rows: rt (h-1), rt+1 (h), rt+2 (h+1)
        float a0[6] = {vl[rt],     vm[rt][0],     vm[rt][1],     vm[rt][2],     vm[rt][3],     vr[rt]};
        float a1[6] = {vl[rt + 1], vm[rt + 1][0], vm[rt + 1][1], vm[rt + 1][2], vm[rt + 1][3], vr[rt + 1]};
        float a2[6] = {vl[rt + 2], vm[rt + 2][0], vm[rt + 2][1], vm[rt + 2][2], vm[rt + 2][3], vr[rt + 2]};
        vfloat4 o;
#pragma unroll
        for (int t = 0; t < 4; ++t) {
            float m;
            m =          a0[t + 0] + w00;
            m = fmaxf(m, a0[t + 1] + w01);
            m = fmaxf(m, a0[t + 2] + w02);
            m = fmaxf(m, a1[t + 0] + w10);
            m = fmaxf(m, a1[t + 1] + w11);
            m = fmaxf(m, a1[t + 2] + w12);
            m = fmaxf(m, a2[t + 0] + w20);
            m = fmaxf(m, a2[t + 1] + w21);
            m = fmaxf(m, a2[t + 2] + w22);
            o[t] = m;
        }
        *reinterpret_cast<vfloat4*>(oplane + (size_t)(h0 + rt) * WW + w4) = o;
    }
}

extern "C" void kernel_launch(void* const* d_in, const int* in_sizes, int n_in,
                              void* d_out, int out_size, void* d_ws, size_t ws_size,
                              hipStream_t stream) {
    const float* x   = (const float*)d_in[0];
    const float* wts = (const float*)d_in[1];
    float* out = (float*)d_out;

    int total_threads = BB * CC * HB * W4;   // 2,097,152
    int block = 256;
    int grid = total_threads / block;        // 8,192
    morph_dilate_kernel<<<grid, block, 0, stream>>>(x, wts, out);
}

// Round 8
// 422.423 us; speedup vs baseline: 1.1166x; 1.0321x over previous
//
#include <hip/hip_runtime.h>

// Morphological dilation (max-plus 3x3 conv), zero-padded.
// x: (B=4, C=64, H=512, W=512) fp32, weights: (C=64, 3, 3) fp32.
// out[b,c,h,w] = max_{i,j in 0..2} ( xp[b,c,h-1+i,w-1+j] + wt[c,i,j] ),
// zero-padded (nn.Unfold semantics) — padded zeros DO participate.
//
// R7: R4's winning structure (aligned float4 mid loads + per-lane scalar
// edge loads + plain cached stores), deepened to 8 rows per thread.
// Halves VMEM instructions per output byte vs R4 (38 per 8KB out vs
// 22 per 4KB). No shuffles (R6's DS-pipe halo swap was a net loss).

#define BB 4
#define CC 64
#define HH 512
#define WW 512
#define W4 (WW / 4)   // 128 col-groups
#define RB 8          // output rows per thread
#define HB (HH / RB)  // 64 row-blocks

typedef float vfloat4 __attribute__((ext_vector_type(4)));

__global__ __launch_bounds__(256) void morph_dilate_kernel(
    const float* __restrict__ x,
    const float* __restrict__ wts,
    float* __restrict__ out) {
    int tid = blockIdx.x * blockDim.x + threadIdx.x;
    // total threads = 256 planes * 64 hb * 128 wi = 2,097,152
    int wi    = tid & (W4 - 1);          // col-group 0..127
    int w4    = wi * 4;
    int hb    = (tid >> 7) & (HB - 1);   // row-block 0..63 (wave-uniform)
    int h0    = hb * RB;
    int plane = tid >> 13;               // b*C + c (wave-uniform)
    int c     = plane & (CC - 1);

    const float* xplane = x + (size_t)plane * (HH * WW);
    const float* wt = wts + c * 9;

    float w00 = wt[0], w01 = wt[1], w02 = wt[2];
    float w10 = wt[3], w11 = wt[4], w12 = wt[5];
    float w20 = wt[6], w21 = wt[7], w22 = wt[8];

    // load 10 input rows (h0-1 .. h0+8): 6 floats each (w4-1 .. w4+4)
    float v[10][6];
#pragma unroll
    for (int i = 0; i < 10; ++i) {
        int r = h0 - 1 + i;               // wave-uniform condition
        if (r >= 0 && r < HH) {
            const float* xrow = xplane + r * WW;
            v[i][0] = (w4 > 0) ? xrow[w4 - 1] : 0.0f;
            vfloat4 mid = *reinterpret_cast<const vfloat4*>(xrow + w4);
            v[i][1] = mid.x; v[i][2] = mid.y; v[i][3] = mid.z; v[i][4] = mid.w;
            v[i][5] = (w4 + 4 < WW) ? xrow[w4 + 4] : 0.0f;
        } else {
#pragma unroll
            for (int j = 0; j < 6; ++j) v[i][j] = 0.0f;
        }
    }

    float* oplane = out + (size_t)plane * (HH * WW);
#pragma unroll
    for (int rt = 0; rt < RB; ++rt) {
        vfloat4 o;
#pragma unroll
        for (int t = 0; t < 4; ++t) {
            float m;
            m =          v[rt + 0][t + 0] + w00;
            m = fmaxf(m, v[rt + 0][t + 1] + w01);
            m = fmaxf(m, v[rt + 0][t + 2] + w02);
            m = fmaxf(m, v[rt + 1][t + 0] + w10);
            m = fmaxf(m, v[rt + 1][t + 1] + w11);
            m = fmaxf(m, v[rt + 1][t + 2] + w12);
            m = fmaxf(m, v[rt + 2][t + 0] + w20);
            m = fmaxf(m, v[rt + 2][t + 1] + w21);
            m = fmaxf(m, v[rt + 2][t + 2] + w22);
            o[t] = m;
        }
        *reinterpret_cast<vfloat4*>(oplane + (size_t)(h0 + rt) * WW + w4) = o;
    }
}

extern "C" void kernel_launch(void* const* d_in, const int* in_sizes, int n_in,
                              void* d_out, int out_size, void* d_ws, size_t ws_size,
                              hipStream_t stream) {
    const float* x   = (const float*)d_in[0];
    const float* wts = (const float*)d_in[1];
    float* out = (float*)d_out;

    int total_threads = BB * CC * HB * W4;   // 2,097,152
    int block = 256;
    int grid = total_threads / block;        // 8,192
    morph_dilate_kernel<<<grid, block, 0, stream>>>(x, wts, out);
}